// Round 14
// baseline (63.430 us; speedup 1.0000x reference)
//
#include <hip/hip_runtime.h>

#define NVEC (64*64*64)   // 262144 vectors
#define KCB 1024          // codebook size
#define DIM 64            // codebook dim
#define VB 128            // vectors per batch
#define BATCHES 4         // batches per block
#define GRID 512          // NVEC / (BATCHES*VB)  -> 2 blocks per CU
#define NSLOT 32          // global count-accumulation slots

typedef __attribute__((ext_vector_type(8))) short s16x8;   // 8 x bf16
typedef __attribute__((ext_vector_type(4))) float f32x4;

#define MFMA16(A, B, C) __builtin_amdgcn_mfma_f32_16x16x32_bf16((A), (B), (C), 0, 0, 0)

// ws layout (bytes):
//      0 : float cnf[1024]                  (ends 4096)
//   4096 : ushort cbA[64][2][64][8]         A-frag bf16(-2c), 131072 B (ends 135168)
// 135168 : float block_partials[512]        (ends 137216) -- per-block loss, NO atomics
// 137216 : uint slots[32][1024]             (ends 268288) -- count accumulators,
//                                           zeroed by vq_prep, 16 RMW/addr only

__global__ __launch_bounds__(256) void vq_prep(const float* __restrict__ cb,
                                               unsigned short* __restrict__ cbA,
                                               float* __restrict__ cnf,
                                               unsigned int* __restrict__ slots) {
    int q = blockIdx.x * 256 + threadIdx.x;      // 0..8191
    ((int4*)slots)[q] = int4{0, 0, 0, 0};         // zero all 32*1024 uints
    int t = q >> 7;
    int h = (q >> 6) & 1;
    int l = q & 63;
    int m = t * 16 + (l & 15);
    int d0 = h * 32 + ((l >> 4) & 3) * 8;
    const float* row = cb + (size_t)m * DIM + d0;
    unsigned short* dst = cbA + (size_t)q * 8;
    #pragma unroll
    for (int j = 0; j < 8; ++j) {
        float f = -2.0f * row[j];
        unsigned u = __float_as_uint(f);
        dst[j] = (unsigned short)((u + 0x7fffu + ((u >> 16) & 1u)) >> 16);  // RNE bf16
    }
    if (q < KCB) {
        const float* r2 = cb + (size_t)q * DIM;
        double s = 0.0;
        for (int d = 0; d < DIM; ++d) { double c = (double)r2[d]; s = fma(c, c, s); }
        cnf[q] = (float)s;
    }
}

// 1024 threads = 16 waves; wave wv holds codes [wv*64, wv*64+64) REGISTER-
// RESIDENT. 2 blocks co-resident per CU (32 waves/CU): independent blocks
// overlap each other's barrier/latency stalls.
__global__ __launch_bounds__(1024) void vq_main(const float* __restrict__ inp,
                                                const unsigned short* __restrict__ cbA,
                                                const float* __restrict__ cnf,
                                                const float* __restrict__ cb,
                                                float* __restrict__ out,
                                                float* __restrict__ partials,
                                                unsigned int* __restrict__ slots) {
    __shared__ unsigned short xf[2][1024][8];  // x B-frags, double-buffered, 32 KB
    __shared__ float xnp[2][1024];             // xnorm partials, 8 KB
    __shared__ float sred[VB][17];             // per-vec per-wave packed best, 8.5 KB
    __shared__ unsigned int histS[KCB];        // per-block count histogram, 4 KB
    __shared__ float lossL[64];

    const int tid  = threadIdx.x;
    const int lane = tid & 63;
    const int wv   = tid >> 6;        // wave 0..15 = code slice
    const int l15  = lane & 15;
    const int g    = lane >> 4;
    const int gi   = g * 4;
    const int blockbase = blockIdx.x * (BATCHES * VB);

    // convert-role constants (ALL 1024 threads): cell tid = (vt*2+h)*64 + l
    const int cvt_vt    = tid >> 7;                          // 0..7
    const int cvt_h     = (tid >> 6) & 1;
    const int cvt_l     = tid & 63;
    const int cvt_vec   = cvt_vt * 16 + (cvt_l & 15);        // vec-in-batch 0..127
    const int cvt_d0    = cvt_h * 32 + (cvt_l >> 4) * 8;     // first of 8 dims
    const int cvt_slice = cvt_h * 4 + (cvt_l >> 4);          // 0..7

    histS[tid] = 0u;   // barrier below orders first use

    // ---- issue batch-0 x loads first (longest latency) ----
    float4 x0{}, x1{};
    {
        const float* xp = inp + (size_t)(blockbase + cvt_vec) * DIM + cvt_d0;
        x0 = ((const float4*)xp)[0];
        x1 = ((const float4*)xp)[1];
    }

    // ---- load this wave's codebook slice into registers (stays forever) ----
    const s16x8* __restrict__ Ap = (const s16x8*)cbA;
    s16x8 A[4][2];
    f32x4 cn[4];
    #pragma unroll
    for (int tt = 0; tt < 4; ++tt) {
        int T = wv * 4 + tt;
        A[tt][0] = Ap[(T * 2 + 0) * 64 + lane];
        A[tt][1] = Ap[(T * 2 + 1) * 64 + lane];
        cn[tt]   = *(const f32x4*)(cnf + T * 16 + gi);
    }

    float loss_acc = 0.0f;

    for (int b = 0; b < BATCHES; ++b) {
        const int buf = b & 1;
        const int vecbase = blockbase + b * VB;

        // ---- convert phase (all threads): x regs -> bf16 frags in LDS ----
        {
            float f[8] = {x0.x, x0.y, x0.z, x0.w, x1.x, x1.y, x1.z, x1.w};
            float xn = 0.f;
            unsigned wq[4];
            #pragma unroll
            for (int p = 0; p < 4; ++p) {
                xn = fmaf(f[2*p], f[2*p], xn);
                xn = fmaf(f[2*p+1], f[2*p+1], xn);
                unsigned r;
                asm("v_cvt_pk_bf16_f32 %0, %1, %2" : "=v"(r) : "v"(f[2*p]), "v"(f[2*p+1]));
                wq[p] = r;
            }
            *(int4*)&xf[buf][tid][0] = *(const int4*)wq;
            xnp[buf][cvt_vec * 8 + cvt_slice] = xn;
        }
        __syncthreads();   // frags ready

        // ---- issue next batch's x loads; held in regs across MFMA phase ----
        if (b + 1 < BATCHES) {
            const float* xp = inp + (size_t)(vecbase + VB + cvt_vec) * DIM + cvt_d0;
            x0 = ((const float4*)xp)[0];
            x1 = ((const float4*)xp)[1];
        }

        // ---- MFMA + argmin: this wave scores 128 vecs vs its 64 codes ----
        float bestv[8];
        #pragma unroll
        for (int vt = 0; vt < 8; ++vt) {
            s16x8 xb0 = *(const s16x8*)&xf[buf][(vt * 2 + 0) * 64 + lane][0];
            s16x8 xb1 = *(const s16x8*)&xf[buf][(vt * 2 + 1) * 64 + lane][0];
            f32x4 a0 = cn[0], a1 = cn[1], a2 = cn[2], a3 = cn[3];
            a0 = MFMA16(A[0][0], xb0, a0);
            a1 = MFMA16(A[1][0], xb0, a1);
            a2 = MFMA16(A[2][0], xb0, a2);
            a3 = MFMA16(A[3][0], xb0, a3);
            a0 = MFMA16(A[0][1], xb1, a0);
            a1 = MFMA16(A[1][1], xb1, a1);
            a2 = MFMA16(A[2][1], xb1, a2);
            a3 = MFMA16(A[3][1], xb1, a3);

            float bv = 3.4e38f;
            // packed argmin: 4 v_and_or + 2 v_min3 per quad
            #define PACKMIN(ACC, TT) {                                                        \
                unsigned cbase = (unsigned)(wv * 64 + (TT) * 16 + gi);                        \
                float p0 = __uint_as_float((__float_as_uint(ACC[0]) & 0xFFFFFC00u) | cbase);  \
                float p1 = __uint_as_float((__float_as_uint(ACC[1]) & 0xFFFFFC00u) | (cbase+1));\
                float p2 = __uint_as_float((__float_as_uint(ACC[2]) & 0xFFFFFC00u) | (cbase+2));\
                float p3 = __uint_as_float((__float_as_uint(ACC[3]) & 0xFFFFFC00u) | (cbase+3));\
                float m01;                                                                    \
                asm("v_min3_f32 %0, %1, %2, %3" : "=v"(m01) : "v"(p0), "v"(p1), "v"(p2));     \
                asm("v_min3_f32 %0, %1, %2, %3" : "=v"(bv) : "v"(m01), "v"(p3), "v"(bv)); }
            PACKMIN(a0, 0) PACKMIN(a1, 1) PACKMIN(a2, 2) PACKMIN(a3, 3)
            #undef PACKMIN
            bestv[vt] = bv;
        }

        // cross-lane-group combine (codes split across g), publish per-wave best
        #pragma unroll
        for (int vt = 0; vt < 8; ++vt) {
            bestv[vt] = fminf(bestv[vt], __shfl_xor(bestv[vt], 16));
            bestv[vt] = fminf(bestv[vt], __shfl_xor(bestv[vt], 32));
        }
        if (g == 0) {
            #pragma unroll
            for (int vt = 0; vt < 8; ++vt) sred[vt * 16 + l15][wv] = bestv[vt];
        }
        __syncthreads();   // sred ready

        // ---- final 16-way reduce + coalesced epilogue (2 reps x 64 vecs) ----
        #pragma unroll
        for (int rep = 0; rep < 2; ++rep) {
            const int vec = rep * 64 + (tid >> 4), sl = tid & 15;
            float pb = sred[vec][sl];
            pb = fminf(pb, __shfl_xor(pb, 1));
            pb = fminf(pb, __shfl_xor(pb, 2));
            pb = fminf(pb, __shfl_xor(pb, 4));
            pb = fminf(pb, __shfl_xor(pb, 8));
            int bk = (int)(__float_as_uint(pb) & 1023u);
            float4 q = ((const float4*)cb)[bk * 16 + sl];
            ((float4*)out)[(size_t)(vecbase + vec) * 16 + sl] = q;
            if (sl == 0) {
                float xn = 0.f;
                #pragma unroll
                for (int j = 0; j < 8; ++j) xn += xnp[buf][vec * 8 + j];
                loss_acc += pb + xn;               // min dist = packed score + ||x||^2
                atomicAdd(&histS[bk], 1u);         // LDS atomic -- no global RMW
            }
        }
        // no barrier: next convert writes xf/xnp[buf^1]; sred rewritten only
        // after the next post-convert barrier.
    }

    // ---- block loss reduction + histogram fold-out ----
    if ((tid & 15) == 0) lossL[tid >> 4] = loss_acc;
    __syncthreads();
    if (tid < 64) {
        float v = lossL[tid];
        #pragma unroll
        for (int off = 32; off > 0; off >>= 1) v += __shfl_xor(v, off);
        if (tid == 0) partials[blockIdx.x] = v;
    }
    unsigned hv = histS[tid];
    if (hv) atomicAdd(&slots[(blockIdx.x & (NSLOT - 1)) * KCB + tid], hv);
}

__global__ __launch_bounds__(1024) void vq_finalize(float* __restrict__ out,
                                                    const float* __restrict__ partials,
                                                    const unsigned int* __restrict__ slots) {
    __shared__ double red[1024];
    const int tid = threadIdx.x;
    unsigned tot = 0;
    #pragma unroll
    for (int s = 0; s < NSLOT; ++s) tot += slots[s * KCB + tid];
    double p = (double)tot / (double)NVEC;
    double h = p * log(p + 1e-10);
    double ls = (tid < GRID) ? (double)partials[tid] : 0.0;

    red[tid] = ls;
    __syncthreads();
    for (int t = 512; t > 0; t >>= 1) {
        if (tid < t) red[tid] += red[tid + t];
        __syncthreads();
    }
    double loss_tot = red[0];
    __syncthreads();
    red[tid] = h;
    __syncthreads();
    for (int t = 512; t > 0; t >>= 1) {
        if (tid < t) red[tid] += red[tid + t];
        __syncthreads();
    }
    if (tid == 0) {
        out[(size_t)NVEC * DIM]     = (float)(0.25 * loss_tot / (double)((size_t)NVEC * DIM));
        out[(size_t)NVEC * DIM + 1] = (float)exp(-red[0]);
    }
}

extern "C" void kernel_launch(void* const* d_in, const int* in_sizes, int n_in,
                              void* d_out, int out_size, void* d_ws, size_t ws_size,
                              hipStream_t stream) {
    const float* inp = (const float*)d_in[0];   // (64,64,64,64) f32
    const float* cb  = (const float*)d_in[1];   // (1024,64) f32
    float* out = (float*)d_out;

    char* ws = (char*)d_ws;
    float*          cnf      = (float*)(ws + 0);
    unsigned short* cbA      = (unsigned short*)(ws + 4096);
    float*          partials = (float*)(ws + 135168);
    unsigned int*   slots    = (unsigned int*)(ws + 137216);

    vq_prep<<<dim3(32), dim3(256), 0, stream>>>(cb, cbA, cnf, slots);
    vq_main<<<dim3(GRID), dim3(1024), 0, stream>>>(inp, cbA, cnf, cb, out,
                                                   partials, slots);
    vq_finalize<<<dim3(1), dim3(1024), 0, stream>>>(out, partials, slots);
}